// Round 1
// baseline (416.351 us; speedup 1.0000x reference)
//
#include <hip/hip_runtime.h>

typedef __attribute__((ext_vector_type(4))) float  f4;
typedef __attribute__((ext_vector_type(8))) short  bf16x8;
typedef __attribute__((ext_vector_type(4))) float  f32x4;
typedef __attribute__((ext_vector_type(4))) unsigned short us4;
typedef __attribute__((ext_vector_type(2))) unsigned int u32x2;

#define BATCH 64
#define FEAT 2048
#define NC_C 112
#define TE 1024          // 2*E
#define EE 512
#define NCLS 345
#define NCLSP 352
#define KHEAD 57344      // C*E

__device__ __forceinline__ unsigned short f2bf(float f) {
    unsigned u = __float_as_uint(f);
    unsigned r = (u + 0x7FFFu + ((u >> 16) & 1u)) >> 16;
    return (unsigned short)r;
}
__device__ __forceinline__ float bf2f(unsigned short h) {
    return __uint_as_float(((unsigned)h) << 16);
}

// ---------------------------------------------------------------------------
// K1: embeddings = x @ W_emb[c] + b_emb   (per c), bf16 MFMA, 64x128 tiles
// grid: 896 = 112 c * 8 n-tiles, block 256 (4 waves, 2x2 over 64x128)
// ---------------------------------------------------------------------------
__global__ __launch_bounds__(256) void k_emb(
    const float* __restrict__ x, const float* __restrict__ W_emb,
    const float* __restrict__ b_emb, unsigned short* __restrict__ emb_bf)
{
    __shared__ __align__(16) unsigned short Alds[64 * 40];   // [row][k] stride 40 halves
    __shared__ __align__(16) unsigned short Blds[128 * 40];  // [n][k] transposed, swizzled

    const int tid = threadIdx.x;
    const int c  = blockIdx.x >> 3;
    const int n0 = (blockIdx.x & 7) * 128;
    const float* __restrict__ Wc = W_emb + (size_t)c * (FEAT * TE);

    const int w = tid >> 6, l = tid & 63;
    const int mbase = (w & 1) * 32, nbase = (w >> 1) * 64;

    // staging maps
    const int a_row = tid >> 3;           // 0..31 (+32 pass 2)
    const int a_k4  = (tid & 7) * 4;
    const int b_kp  = tid >> 4;           // 0..15 (k = 2kp, 2kp+1)
    const int b_n4  = (tid & 15) * 4;     // 0..60 (+64 pass 2)

    f4 a0, a1, pA0, pB0, pA1, pB1;
    {   // prefetch step 0
        const float* ax = x + (size_t)a_row * FEAT + a_k4;
        a0 = *(const f4*)ax;
        a1 = *(const f4*)(ax + 32 * FEAT);
        const float* bp = Wc + (size_t)(2 * b_kp) * TE + n0 + b_n4;
        pA0 = *(const f4*)bp;           pB0 = *(const f4*)(bp + TE);
        pA1 = *(const f4*)(bp + 64);    pB1 = *(const f4*)(bp + TE + 64);
    }

    f32x4 acc[2][4];
#pragma unroll
    for (int i = 0; i < 2; ++i)
#pragma unroll
        for (int j = 0; j < 4; ++j) acc[i][j] = (f32x4){0.f, 0.f, 0.f, 0.f};

    for (int s = 0; s < 64; ++s) {
        __syncthreads();  // previous step's LDS reads done
        // --- write LDS from prefetched regs ---
        {   // A: linear [row][k], b64 writes
            u32x2 v0, v1;
            v0[0] = (unsigned)f2bf(a0[0]) | ((unsigned)f2bf(a0[1]) << 16);
            v0[1] = (unsigned)f2bf(a0[2]) | ((unsigned)f2bf(a0[3]) << 16);
            v1[0] = (unsigned)f2bf(a1[0]) | ((unsigned)f2bf(a1[1]) << 16);
            v1[1] = (unsigned)f2bf(a1[2]) | ((unsigned)f2bf(a1[3]) << 16);
            *(u32x2*)&Alds[a_row * 40 + a_k4] = v0;
            *(u32x2*)&Alds[(a_row + 32) * 40 + a_k4] = v1;
        }
        {   // B: transposed [n][k], pair-packed b32 writes, octet swizzle
            const int koct = b_kp >> 2;
            const int klo  = (2 * b_kp) & 7;
#pragma unroll
            for (int i = 0; i < 4; ++i) {
                int n = b_n4 + i;
                unsigned v = (unsigned)f2bf(pA0[i]) | ((unsigned)f2bf(pB0[i]) << 16);
                *(unsigned*)&Blds[n * 40 + (((koct ^ ((n >> 2) & 3)) << 3) | klo)] = v;
                n += 64;
                unsigned v2 = (unsigned)f2bf(pA1[i]) | ((unsigned)f2bf(pB1[i]) << 16);
                *(unsigned*)&Blds[n * 40 + (((koct ^ ((n >> 2) & 3)) << 3) | klo)] = v2;
            }
        }
        __syncthreads();

        if (s < 63) {  // prefetch next step (hides under MFMA below)
            const int k0 = (s + 1) * 32;
            const float* ax = x + (size_t)a_row * FEAT + k0 + a_k4;
            a0 = *(const f4*)ax;
            a1 = *(const f4*)(ax + 32 * FEAT);
            const float* bp = Wc + (size_t)(k0 + 2 * b_kp) * TE + n0 + b_n4;
            pA0 = *(const f4*)bp;           pB0 = *(const f4*)(bp + TE);
            pA1 = *(const f4*)(bp + 64);    pB1 = *(const f4*)(bp + TE + 64);
        }

        // --- fragments + MFMA ---
        bf16x8 af[2], bfr[4];
#pragma unroll
        for (int si = 0; si < 2; ++si)
            af[si] = *(const bf16x8*)&Alds[(mbase + si * 16 + (l & 15)) * 40 + (l >> 4) * 8];
#pragma unroll
        for (int nf = 0; nf < 4; ++nf) {
            int n = nbase + nf * 16 + (l & 15);
            bfr[nf] = *(const bf16x8*)&Blds[n * 40 + (((l >> 4) ^ ((n >> 2) & 3)) << 3)];
        }
#pragma unroll
        for (int si = 0; si < 2; ++si)
#pragma unroll
            for (int nf = 0; nf < 4; ++nf)
                acc[si][nf] = __builtin_amdgcn_mfma_f32_16x16x32_bf16(
                    af[si], bfr[nf], acc[si][nf], 0, 0, 0);
    }

    // epilogue: + b_emb, store bf16 to ws  (emb layout [b][c][e])
#pragma unroll
    for (int si = 0; si < 2; ++si)
#pragma unroll
        for (int nf = 0; nf < 4; ++nf) {
            const int nl = nbase + nf * 16 + (l & 15);
            const int ng = n0 + nl;
            const float bias = b_emb[c * TE + ng];
#pragma unroll
            for (int r = 0; r < 4; ++r) {
                const int bb = mbase + si * 16 + (l >> 4) * 4 + r;
                const float v = acc[si][nf][r] + bias;
                emb_bf[((size_t)bb * NC_C + c) * TE + ng] = f2bf(v);
            }
        }
}

// ---------------------------------------------------------------------------
// K2: p_int = sigmoid(emb . W_pint + b_pint); mixed = p*pos + (1-p)*neg
// one wave per (b,c); grid 1792 * 256
// ---------------------------------------------------------------------------
__global__ __launch_bounds__(256) void k_mix(
    const unsigned short* __restrict__ emb_bf, const float* __restrict__ W_pint,
    const float* __restrict__ b_pint, float* __restrict__ flat_out,
    float* __restrict__ p_out)
{
    const int tid = threadIdx.x;
    const int l = tid & 63, w = tid >> 6;
    const int pidx = blockIdx.x * 4 + w;           // 0..7167
    const int b = pidx / NC_C, c = pidx - b * NC_C;

    const unsigned short* __restrict__ row = emb_bf + ((size_t)b * NC_C + c) * TE;
    const float* __restrict__ wp = W_pint + c * TE;

    float vals[16];
    float dot = 0.f;
#pragma unroll
    for (int i = 0; i < 4; ++i) {
        const int e = 4 * l + 256 * i;
        us4 u = *(const us4*)&row[e];
        f4  wv = *(const f4*)&wp[e];
#pragma unroll
        for (int j = 0; j < 4; ++j) {
            float f = bf2f(u[j]);
            vals[i * 4 + j] = f;
            dot += f * wv[j];
        }
    }
#pragma unroll
    for (int m = 32; m >= 1; m >>= 1) dot += __shfl_xor(dot, m);
    const float logit = dot + b_pint[c];
    const float p = 1.f / (1.f + __expf(-logit));
    if (l == 0) p_out[b * NC_C + c] = p;

    float* __restrict__ fo = flat_out + (size_t)b * KHEAD + c * EE;
#pragma unroll
    for (int i = 0; i < 2; ++i) {
        const int e = 4 * l + 256 * i;
        f4 m;
#pragma unroll
        for (int j = 0; j < 4; ++j)
            m[j] = p * vals[i * 4 + j] + (1.f - p) * vals[(i + 2) * 4 + j];
        *(f4*)&fo[e] = m;
    }
}

// ---------------------------------------------------------------------------
// K3: final = b_head (broadcast init for split-K atomics)
// ---------------------------------------------------------------------------
__global__ __launch_bounds__(256) void k_init(
    const float* __restrict__ b_head, float* __restrict__ final_out)
{
    const int i = blockIdx.x * 256 + threadIdx.x;
    if (i < BATCH * NCLS) final_out[i] = b_head[i % NCLS];
}

// ---------------------------------------------------------------------------
// K4: final += flat @ W_head, split-K (224 blocks, K-slice 256), bf16 MFMA
// ---------------------------------------------------------------------------
__global__ __launch_bounds__(256) void k_head(
    const float* __restrict__ flat, const float* __restrict__ W_head,
    float* __restrict__ final_out)
{
    __shared__ __align__(16) unsigned short Blds[NCLSP * 40];  // [n][k] swizzled

    const int tid = threadIdx.x;
    const int w = tid >> 6, l = tid & 63;
    const int k0 = blockIdx.x * 256;

    f32x4 acc[22];
#pragma unroll
    for (int i = 0; i < 22; ++i) acc[i] = (f32x4){0.f, 0.f, 0.f, 0.f};

    for (int s = 0; s < 8; ++s) {
        const int kb = k0 + s * 32;
        __syncthreads();
        for (int idx = tid; idx < 32 * NCLSP; idx += 256) {
            const int k = idx / NCLSP;
            const int n = idx - k * NCLSP;
            const float v = (n < NCLS) ? W_head[(size_t)(kb + k) * NCLS + n] : 0.f;
            Blds[n * 40 + ((((k >> 3) ^ ((n >> 2) & 3)) << 3) | (k & 7))] = f2bf(v);
        }
        __syncthreads();

        // A-frag direct from global f32 (L2-hot), convert in-register
        const float* __restrict__ ap =
            flat + (size_t)(w * 16 + (l & 15)) * KHEAD + kb + (l >> 4) * 8;
        f4 af0 = *(const f4*)ap;
        f4 af1 = *(const f4*)(ap + 4);
        bf16x8 a;
        a[0] = (short)f2bf(af0[0]); a[1] = (short)f2bf(af0[1]);
        a[2] = (short)f2bf(af0[2]); a[3] = (short)f2bf(af0[3]);
        a[4] = (short)f2bf(af1[0]); a[5] = (short)f2bf(af1[1]);
        a[6] = (short)f2bf(af1[2]); a[7] = (short)f2bf(af1[3]);

#pragma unroll
        for (int nf = 0; nf < 22; ++nf) {
            const int n = nf * 16 + (l & 15);
            bf16x8 bfr = *(const bf16x8*)&Blds[n * 40 + (((l >> 4) ^ ((n >> 2) & 3)) << 3)];
            acc[nf] = __builtin_amdgcn_mfma_f32_16x16x32_bf16(a, bfr, acc[nf], 0, 0, 0);
        }
    }

#pragma unroll
    for (int nf = 0; nf < 22; ++nf) {
        const int n = nf * 16 + (l & 15);
        if (n < NCLS) {
#pragma unroll
            for (int r = 0; r < 4; ++r) {
                const int row = w * 16 + (l >> 4) * 4 + r;
                atomicAdd(&final_out[row * NCLS + n], acc[nf][r]);
            }
        }
    }
}

extern "C" void kernel_launch(void* const* d_in, const int* in_sizes, int n_in,
                              void* d_out, int out_size, void* d_ws, size_t ws_size,
                              hipStream_t stream) {
    const float* x      = (const float*)d_in[0];
    const float* W_emb  = (const float*)d_in[1];
    const float* b_emb  = (const float*)d_in[2];
    const float* W_pint = (const float*)d_in[3];
    const float* b_pint = (const float*)d_in[4];
    const float* W_head = (const float*)d_in[5];
    const float* b_head = (const float*)d_in[6];

    float* out   = (float*)d_out;
    float* final_out = out;                                   // 64*345
    float* flat  = out + BATCH * NCLS;                        // 64*57344
    float* p_out = out + BATCH * NCLS + BATCH * KHEAD;        // 64*112

    unsigned short* emb_bf = (unsigned short*)d_ws;           // 64*112*1024 bf16

    k_init<<<(BATCH * NCLS + 255) / 256, 256, 0, stream>>>(b_head, final_out);
    k_emb<<<NC_C * 8, 256, 0, stream>>>(x, W_emb, b_emb, emb_bf);
    k_mix<<<(BATCH * NC_C) / 4, 256, 0, stream>>>(emb_bf, W_pint, b_pint, flat, p_out);
    k_head<<<KHEAD / 256, 256, 0, stream>>>(flat, W_head, final_out);
}